// Round 1
// baseline (873.866 us; speedup 1.0000x reference)
//
#include <hip/hip_runtime.h>

#define N_NODES 100000
#define N_EDGES 640000
#define HID 128
#define N_CLASSES 40
#define N_GRAPHS 128
#define BN_EPS 1e-5f

// ---------------------------------------------------------------------------
// degree / CSR construction
// ---------------------------------------------------------------------------
__global__ void count_kernel(const int* __restrict__ row, const int* __restrict__ col,
                             int* degcnt, int* cnt, int E) {
    int e = blockIdx.x * 256 + threadIdx.x;
    if (e < E) {
        atomicAdd(&degcnt[row[e]], 1);
        atomicAdd(&cnt[col[e]], 1);
    }
}

__global__ void dinv_kernel(const int* __restrict__ degcnt, float* __restrict__ dinv, int n) {
    int i = blockIdx.x * 256 + threadIdx.x;
    if (i < n) dinv[i] = rsqrtf((float)degcnt[i] + 1.0f);
}

// block-level exclusive scan (1024 elements per block of 256 threads)
__global__ __launch_bounds__(256) void scanA(const int* __restrict__ cnt, int* __restrict__ rowptr,
                                             int* __restrict__ blockSums, int n) {
    __shared__ int sdata[256];
    int t = threadIdx.x;
    int base = blockIdx.x * 1024 + t * 4;
    int c[4];
#pragma unroll
    for (int j = 0; j < 4; ++j) c[j] = (base + j < n) ? cnt[base + j] : 0;
    int s = c[0] + c[1] + c[2] + c[3];
    sdata[t] = s;
    __syncthreads();
    for (int off = 1; off < 256; off <<= 1) {
        int v = (t >= off) ? sdata[t - off] : 0;
        __syncthreads();
        sdata[t] += v;
        __syncthreads();
    }
    int excl = sdata[t] - s;
    if (t == 255) blockSums[blockIdx.x] = sdata[255];
    int run = excl;
#pragma unroll
    for (int j = 0; j < 4; ++j) {
        if (base + j < n) rowptr[base + j] = run;
        run += c[j];
    }
}

__global__ void scanB(const int* __restrict__ blockSums, int* __restrict__ blockOffs, int nb) {
    __shared__ int sdata[128];
    int t = threadIdx.x;
    int v = (t < nb) ? blockSums[t] : 0;
    sdata[t] = v;
    __syncthreads();
    for (int off = 1; off < 128; off <<= 1) {
        int u = (t >= off) ? sdata[t - off] : 0;
        __syncthreads();
        sdata[t] += u;
        __syncthreads();
    }
    if (t < nb) blockOffs[t] = sdata[t] - v;
}

__global__ void scanC(int* __restrict__ rowptr, const int* __restrict__ blockOffs,
                      int* __restrict__ wptr, int n) {
    int i = blockIdx.x * 256 + threadIdx.x;
    if (i < n) {
        int v = rowptr[i] + blockOffs[i >> 10];
        rowptr[i] = v;
        wptr[i] = v;
    }
}

__global__ void fill_kernel(const int* __restrict__ row, const int* __restrict__ col,
                            int* wptr, int* __restrict__ srcIdx, int E) {
    int e = blockIdx.x * 256 + threadIdx.x;
    if (e < E) {
        int p = atomicAdd(&wptr[col[e]], 1);
        srcIdx[p] = row[e];
    }
}

// ---------------------------------------------------------------------------
// GEMM: out[N x 128] = f(in)[N x 128] @ W[128 x 128]
// f = identity, or BN(scale,shift)+ReLU fused on input load when useBN!=0.
// Block: 256 threads, 64 rows x 128 cols tile. W cached in LDS (64 KB).
// Thread (rg,cg): rows rg*4..+3, cols cg*4..+3 and cg*4+64..+67.
// ---------------------------------------------------------------------------
__global__ __launch_bounds__(256, 2) void gemm128(
    const float* __restrict__ in, const float* __restrict__ W,
    const float* __restrict__ bn_s, const float* __restrict__ bn_t,
    float* __restrict__ out, int nRows, int useBN) {
    __shared__ float Wl[128 * 128];  // 64 KB
    {
        const float4* Ws = (const float4*)W;
        float4* Wd = (float4*)Wl;
        for (int i = threadIdx.x; i < 128 * 128 / 4; i += 256) Wd[i] = Ws[i];
    }
    __syncthreads();

    const int cg = threadIdx.x & 15;
    const int rg = threadIdx.x >> 4;
    const int c0 = cg * 4;
    const long base_row = (long)blockIdx.x * 64 + rg * 4;

    float acc[4][8];
#pragma unroll
    for (int i = 0; i < 4; ++i)
#pragma unroll
        for (int j = 0; j < 8; ++j) acc[i][j] = 0.f;

    for (int kq = 0; kq < 32; ++kq) {
        float4 a[4];
#pragma unroll
        for (int i = 0; i < 4; ++i) {
            long r = base_row + i;
            a[i] = (r < nRows) ? *(const float4*)&in[r * 128 + kq * 4]
                               : make_float4(0.f, 0.f, 0.f, 0.f);
        }
        if (useBN) {
            float4 sv = *(const float4*)&bn_s[kq * 4];
            float4 tv = *(const float4*)&bn_t[kq * 4];
#pragma unroll
            for (int i = 0; i < 4; ++i) {
                a[i].x = fmaxf(fmaf(a[i].x, sv.x, tv.x), 0.f);
                a[i].y = fmaxf(fmaf(a[i].y, sv.y, tv.y), 0.f);
                a[i].z = fmaxf(fmaf(a[i].z, sv.z, tv.z), 0.f);
                a[i].w = fmaxf(fmaf(a[i].w, sv.w, tv.w), 0.f);
            }
        }
#pragma unroll
        for (int c = 0; c < 4; ++c) {
            int k = kq * 4 + c;
            float4 w0 = *(const float4*)&Wl[k * 128 + c0];
            float4 w1 = *(const float4*)&Wl[k * 128 + c0 + 64];
#pragma unroll
            for (int i = 0; i < 4; ++i) {
                float av = (c == 0) ? a[i].x : (c == 1) ? a[i].y : (c == 2) ? a[i].z : a[i].w;
                acc[i][0] = fmaf(av, w0.x, acc[i][0]);
                acc[i][1] = fmaf(av, w0.y, acc[i][1]);
                acc[i][2] = fmaf(av, w0.z, acc[i][2]);
                acc[i][3] = fmaf(av, w0.w, acc[i][3]);
                acc[i][4] = fmaf(av, w1.x, acc[i][4]);
                acc[i][5] = fmaf(av, w1.y, acc[i][5]);
                acc[i][6] = fmaf(av, w1.z, acc[i][6]);
                acc[i][7] = fmaf(av, w1.w, acc[i][7]);
            }
        }
    }
#pragma unroll
    for (int i = 0; i < 4; ++i) {
        long r = base_row + i;
        if (r < nRows) {
            *(float4*)&out[r * 128 + c0] =
                make_float4(acc[i][0], acc[i][1], acc[i][2], acc[i][3]);
            *(float4*)&out[r * 128 + c0 + 64] =
                make_float4(acc[i][4], acc[i][5], acc[i][6], acc[i][7]);
        }
    }
}

// ---------------------------------------------------------------------------
// Aggregation: out[v] = dinv[v] * sum_{e in CSR(v)} dinv[src_e] * h[src_e]
// One wave (64 lanes) per node; lane holds 2 features (float2). No atomics.
// ---------------------------------------------------------------------------
__global__ __launch_bounds__(256) void agg_kernel(
    const float* __restrict__ h, const int* __restrict__ rowptr,
    const int* __restrict__ cnt, const int* __restrict__ srcIdx,
    const float* __restrict__ dinv, float* __restrict__ out, int nNodes) {
    int wave = threadIdx.x >> 6;
    int lane = threadIdx.x & 63;
    int v = blockIdx.x * 4 + wave;
    if (v >= nNodes) return;
    int start = rowptr[v];
    int n = cnt[v];
    float ax = 0.f, ay = 0.f;
    for (int e = 0; e < n; ++e) {
        int src = srcIdx[start + e];
        float w = dinv[src];
        float2 hv = *(const float2*)&h[(long)src * 128 + lane * 2];
        ax = fmaf(w, hv.x, ax);
        ay = fmaf(w, hv.y, ay);
    }
    float dv = dinv[v];
    *(float2*)&out[(long)v * 128 + lane * 2] = make_float2(ax * dv, ay * dv);
}

// ---------------------------------------------------------------------------
// BN statistics: per-column sum and sum-of-squares via block partials + atomics
// ---------------------------------------------------------------------------
__global__ __launch_bounds__(256) void bnstats(const float* __restrict__ h,
                                               float* __restrict__ sums, int nRows) {
    int col = threadIdx.x & 127;
    int half = threadIdx.x >> 7;
    int chunk = (nRows + gridDim.x - 1) / gridDim.x;
    int r0 = blockIdx.x * chunk;
    int r1 = min(r0 + chunk, nRows);
    float s = 0.f, s2 = 0.f;
    for (int r = r0 + half; r < r1; r += 2) {
        float v = h[(long)r * 128 + col];
        s += v;
        s2 = fmaf(v, v, s2);
    }
    __shared__ float l1[256], l2[256];
    l1[threadIdx.x] = s;
    l2[threadIdx.x] = s2;
    __syncthreads();
    if (half == 0) {
        s = l1[threadIdx.x] + l1[threadIdx.x + 128];
        s2 = l2[threadIdx.x] + l2[threadIdx.x + 128];
        atomicAdd(&sums[col], s);
        atomicAdd(&sums[128 + col], s2);
    }
}

__global__ void bnfin(const float* __restrict__ sums, const float* __restrict__ gamma,
                      const float* __restrict__ beta, float* __restrict__ bn_s,
                      float* __restrict__ bn_t, float invN) {
    int c = threadIdx.x;
    float mean = sums[c] * invN;
    float var = sums[128 + c] * invN - mean * mean;
    float rs = rsqrtf(var + BN_EPS);
    float s = gamma[c] * rs;
    bn_s[c] = s;
    bn_t[c] = beta[c] - mean * s;
}

// ---------------------------------------------------------------------------
// Global mean pool per graph (batch sorted -> binary search the node range)
// ---------------------------------------------------------------------------
__global__ __launch_bounds__(128) void pool_kernel(const float* __restrict__ h,
                                                   const int* __restrict__ batch,
                                                   float* __restrict__ xg, int nNodes) {
    int g = blockIdx.x;
    int a = 0, b = nNodes;
    while (a < b) { int m = (a + b) >> 1; if (batch[m] < g) a = m + 1; else b = m; }
    int lo = a;
    b = nNodes;
    while (a < b) { int m = (a + b) >> 1; if (batch[m] < g + 1) a = m + 1; else b = m; }
    int hi = a;
    float acc = 0.f;
    for (int v = lo; v < hi; ++v) acc += h[(long)v * 128 + threadIdx.x];
    float c = (float)(hi - lo);
    xg[g * 128 + threadIdx.x] = acc / fmaxf(c, 1.0f);
}

// ---------------------------------------------------------------------------
// MLP head: relu(xg@Wg1+bg1) @ Wg2 + bg2 -> log_softmax
// ---------------------------------------------------------------------------
__global__ __launch_bounds__(128) void head_kernel(
    const float* __restrict__ xg, const float* __restrict__ Wg1,
    const float* __restrict__ bg1, const float* __restrict__ Wg2,
    const float* __restrict__ bg2, float* __restrict__ out) {
    __shared__ float xr[128], tr[128], lg[N_CLASSES], red[2];
    int g = blockIdx.x, t = threadIdx.x;
    xr[t] = xg[g * 128 + t];
    __syncthreads();
    float s = bg1[t];
    for (int k = 0; k < 128; ++k) s = fmaf(xr[k], Wg1[k * 128 + t], s);
    tr[t] = fmaxf(s, 0.f);
    __syncthreads();
    if (t < N_CLASSES) {
        float s2 = bg2[t];
        for (int k = 0; k < 128; ++k) s2 = fmaf(tr[k], Wg2[k * N_CLASSES + t], s2);
        lg[t] = s2;
    }
    __syncthreads();
    if (t == 0) {
        float m = -1e30f;
        for (int j = 0; j < N_CLASSES; ++j) m = fmaxf(m, lg[j]);
        float se = 0.f;
        for (int j = 0; j < N_CLASSES; ++j) se += expf(lg[j] - m);
        red[0] = m;
        red[1] = logf(se);
    }
    __syncthreads();
    if (t < N_CLASSES) out[g * N_CLASSES + t] = lg[t] - red[0] - red[1];
}

// ---------------------------------------------------------------------------
extern "C" void kernel_launch(void* const* d_in, const int* in_sizes, int n_in,
                              void* d_out, int out_size, void* d_ws, size_t ws_size,
                              hipStream_t stream) {
    const float* x = (const float*)d_in[0];
    const int* edge = (const int*)d_in[1];
    const int* row = edge;
    const int* col = edge + N_EDGES;
    const int* batch = (const int*)d_in[2];
    const float* W0 = (const float*)d_in[3];
    const float* g0 = (const float*)d_in[4];
    const float* b0 = (const float*)d_in[5];
    const float* W1 = (const float*)d_in[6];
    const float* g1 = (const float*)d_in[7];
    const float* b1 = (const float*)d_in[8];
    const float* W2 = (const float*)d_in[9];
    const float* Wg1 = (const float*)d_in[10];
    const float* bg1 = (const float*)d_in[11];
    const float* Wg2 = (const float*)d_in[12];
    const float* bg2 = (const float*)d_in[13];
    float* out = (float*)d_out;

    char* p = (char*)d_ws;
    auto alloc = [&](size_t bytes) {
        void* r = (void*)p;
        p += (bytes + 255) & ~(size_t)255;
        return r;
    };
    float* bufA = (float*)alloc((size_t)N_NODES * 128 * 4);
    float* bufB = (float*)alloc((size_t)N_NODES * 128 * 4);
    float* dinv = (float*)alloc((size_t)N_NODES * 4);
    int* degcnt = (int*)alloc((size_t)N_NODES * 4);
    int* cnt = (int*)alloc((size_t)N_NODES * 4);
    int* rowptr = (int*)alloc((size_t)N_NODES * 4);
    int* wptr = (int*)alloc((size_t)N_NODES * 4);
    int* srcIdx = (int*)alloc((size_t)N_EDGES * 4);
    int* blockSums = (int*)alloc(1024 * 4);
    int* blockOffs = (int*)alloc(1024 * 4);
    float* bnacc = (float*)alloc(256 * 4);
    float* bn_s = (float*)alloc(128 * 4);
    float* bn_t = (float*)alloc(128 * 4);
    float* xg = (float*)alloc(128 * 128 * 4);

    const int E = N_EDGES, N = N_NODES;
    const int scanBlocks = (N + 1023) / 1024;  // 98

    // --- degree + CSR (recomputed every call: deterministic work) ---
    hipMemsetAsync(degcnt, 0, (size_t)N * 4, stream);
    hipMemsetAsync(cnt, 0, (size_t)N * 4, stream);
    count_kernel<<<(E + 255) / 256, 256, 0, stream>>>(row, col, degcnt, cnt, E);
    dinv_kernel<<<(N + 255) / 256, 256, 0, stream>>>(degcnt, dinv, N);
    scanA<<<scanBlocks, 256, 0, stream>>>(cnt, rowptr, blockSums, N);
    scanB<<<1, 128, 0, stream>>>(blockSums, blockOffs, scanBlocks);
    scanC<<<(N + 255) / 256, 256, 0, stream>>>(rowptr, blockOffs, wptr, N);
    fill_kernel<<<(E + 255) / 256, 256, 0, stream>>>(row, col, wptr, srcIdx, E);

    const int gemmGrid = (N + 63) / 64;   // 1563
    const int aggGrid = (N + 3) / 4;      // 25000

    // --- layer 1 ---
    gemm128<<<gemmGrid, 256, 0, stream>>>(x, W0, nullptr, nullptr, bufA, N, 0);
    agg_kernel<<<aggGrid, 256, 0, stream>>>(bufA, rowptr, cnt, srcIdx, dinv, bufB, N);
    hipMemsetAsync(bnacc, 0, 256 * 4, stream);
    bnstats<<<512, 256, 0, stream>>>(bufB, bnacc, N);
    bnfin<<<1, 128, 0, stream>>>(bnacc, g0, b0, bn_s, bn_t, 1.0f / N);

    // --- layer 2 ---
    gemm128<<<gemmGrid, 256, 0, stream>>>(bufB, W1, bn_s, bn_t, bufA, N, 1);
    agg_kernel<<<aggGrid, 256, 0, stream>>>(bufA, rowptr, cnt, srcIdx, dinv, bufB, N);
    hipMemsetAsync(bnacc, 0, 256 * 4, stream);
    bnstats<<<512, 256, 0, stream>>>(bufB, bnacc, N);
    bnfin<<<1, 128, 0, stream>>>(bnacc, g1, b1, bn_s, bn_t, 1.0f / N);

    // --- layer 3 ---
    gemm128<<<gemmGrid, 256, 0, stream>>>(bufB, W2, bn_s, bn_t, bufA, N, 1);
    agg_kernel<<<aggGrid, 256, 0, stream>>>(bufA, rowptr, cnt, srcIdx, dinv, bufB, N);

    // --- pool + head ---
    pool_kernel<<<N_GRAPHS, 128, 0, stream>>>(bufB, batch, xg, N);
    head_kernel<<<N_GRAPHS, 128, 0, stream>>>(xg, Wg1, bg1, Wg2, bg2, out);
}

// Round 2
// 690.506 us; speedup vs baseline: 1.2655x; 1.2655x over previous
//
#include <hip/hip_runtime.h>

#define N_NODES 100000
#define N_EDGES 640000
#define HID 128
#define N_CLASSES 40
#define N_GRAPHS 128
#define BN_EPS 1e-5f
#define POOL_SLICES 16

// ---------------------------------------------------------------------------
// degree / CSR construction
// ---------------------------------------------------------------------------
__global__ void count_kernel(const int* __restrict__ row, const int* __restrict__ col,
                             int* degcnt, int* cnt, int E) {
    int e = blockIdx.x * 256 + threadIdx.x;
    if (e < E) {
        atomicAdd(&degcnt[row[e]], 1);
        atomicAdd(&cnt[col[e]], 1);
    }
}

__global__ void dinv_kernel(const int* __restrict__ degcnt, float* __restrict__ dinv, int n) {
    int i = blockIdx.x * 256 + threadIdx.x;
    if (i < n) dinv[i] = rsqrtf((float)degcnt[i] + 1.0f);
}

// block-level exclusive scan (1024 elements per block of 256 threads)
__global__ __launch_bounds__(256) void scanA(const int* __restrict__ cnt, int* __restrict__ rowptr,
                                             int* __restrict__ blockSums, int n) {
    __shared__ int sdata[256];
    int t = threadIdx.x;
    int base = blockIdx.x * 1024 + t * 4;
    int c[4];
#pragma unroll
    for (int j = 0; j < 4; ++j) c[j] = (base + j < n) ? cnt[base + j] : 0;
    int s = c[0] + c[1] + c[2] + c[3];
    sdata[t] = s;
    __syncthreads();
    for (int off = 1; off < 256; off <<= 1) {
        int v = (t >= off) ? sdata[t - off] : 0;
        __syncthreads();
        sdata[t] += v;
        __syncthreads();
    }
    int excl = sdata[t] - s;
    if (t == 255) blockSums[blockIdx.x] = sdata[255];
    int run = excl;
#pragma unroll
    for (int j = 0; j < 4; ++j) {
        if (base + j < n) rowptr[base + j] = run;
        run += c[j];
    }
}

__global__ void scanB(const int* __restrict__ blockSums, int* __restrict__ blockOffs, int nb) {
    __shared__ int sdata[128];
    int t = threadIdx.x;
    int v = (t < nb) ? blockSums[t] : 0;
    sdata[t] = v;
    __syncthreads();
    for (int off = 1; off < 128; off <<= 1) {
        int u = (t >= off) ? sdata[t - off] : 0;
        __syncthreads();
        sdata[t] += u;
        __syncthreads();
    }
    if (t < nb) blockOffs[t] = sdata[t] - v;
}

__global__ void scanC(int* __restrict__ rowptr, const int* __restrict__ blockOffs,
                      int* __restrict__ wptr, int n) {
    int i = blockIdx.x * 256 + threadIdx.x;
    if (i < n) {
        int v = rowptr[i] + blockOffs[i >> 10];
        rowptr[i] = v;
        wptr[i] = v;
    }
}

__global__ void fill_kernel(const int* __restrict__ row, const int* __restrict__ col,
                            int* wptr, int* __restrict__ srcIdx, int E) {
    int e = blockIdx.x * 256 + threadIdx.x;
    if (e < E) {
        int p = atomicAdd(&wptr[col[e]], 1);
        srcIdx[p] = row[e];
    }
}

// ---------------------------------------------------------------------------
// GEMM: out[N x 128] = f(in)[N x 128] @ W[128 x 128]
// f = identity, or BN(scale,shift)+ReLU fused on input load when useBN!=0.
// ---------------------------------------------------------------------------
__global__ __launch_bounds__(256, 2) void gemm128(
    const float* __restrict__ in, const float* __restrict__ W,
    const float* __restrict__ bn_s, const float* __restrict__ bn_t,
    float* __restrict__ out, int nRows, int useBN) {
    __shared__ float Wl[128 * 128];  // 64 KB
    {
        const float4* Ws = (const float4*)W;
        float4* Wd = (float4*)Wl;
        for (int i = threadIdx.x; i < 128 * 128 / 4; i += 256) Wd[i] = Ws[i];
    }
    __syncthreads();

    const int cg = threadIdx.x & 15;
    const int rg = threadIdx.x >> 4;
    const int c0 = cg * 4;
    const long base_row = (long)blockIdx.x * 64 + rg * 4;

    float acc[4][8];
#pragma unroll
    for (int i = 0; i < 4; ++i)
#pragma unroll
        for (int j = 0; j < 8; ++j) acc[i][j] = 0.f;

    for (int kq = 0; kq < 32; ++kq) {
        float4 a[4];
#pragma unroll
        for (int i = 0; i < 4; ++i) {
            long r = base_row + i;
            a[i] = (r < nRows) ? *(const float4*)&in[r * 128 + kq * 4]
                               : make_float4(0.f, 0.f, 0.f, 0.f);
        }
        if (useBN) {
            float4 sv = *(const float4*)&bn_s[kq * 4];
            float4 tv = *(const float4*)&bn_t[kq * 4];
#pragma unroll
            for (int i = 0; i < 4; ++i) {
                a[i].x = fmaxf(fmaf(a[i].x, sv.x, tv.x), 0.f);
                a[i].y = fmaxf(fmaf(a[i].y, sv.y, tv.y), 0.f);
                a[i].z = fmaxf(fmaf(a[i].z, sv.z, tv.z), 0.f);
                a[i].w = fmaxf(fmaf(a[i].w, sv.w, tv.w), 0.f);
            }
        }
#pragma unroll
        for (int c = 0; c < 4; ++c) {
            int k = kq * 4 + c;
            float4 w0 = *(const float4*)&Wl[k * 128 + c0];
            float4 w1 = *(const float4*)&Wl[k * 128 + c0 + 64];
#pragma unroll
            for (int i = 0; i < 4; ++i) {
                float av = (c == 0) ? a[i].x : (c == 1) ? a[i].y : (c == 2) ? a[i].z : a[i].w;
                acc[i][0] = fmaf(av, w0.x, acc[i][0]);
                acc[i][1] = fmaf(av, w0.y, acc[i][1]);
                acc[i][2] = fmaf(av, w0.z, acc[i][2]);
                acc[i][3] = fmaf(av, w0.w, acc[i][3]);
                acc[i][4] = fmaf(av, w1.x, acc[i][4]);
                acc[i][5] = fmaf(av, w1.y, acc[i][5]);
                acc[i][6] = fmaf(av, w1.z, acc[i][6]);
                acc[i][7] = fmaf(av, w1.w, acc[i][7]);
            }
        }
    }
#pragma unroll
    for (int i = 0; i < 4; ++i) {
        long r = base_row + i;
        if (r < nRows) {
            *(float4*)&out[r * 128 + c0] =
                make_float4(acc[i][0], acc[i][1], acc[i][2], acc[i][3]);
            *(float4*)&out[r * 128 + c0 + 64] =
                make_float4(acc[i][4], acc[i][5], acc[i][6], acc[i][7]);
        }
    }
}

// ---------------------------------------------------------------------------
// Aggregation: out[v] = dinv[v] * sum_{e in CSR(v)} dinv[src_e] * h[src_e]
// One wave (64 lanes) per node; lane holds 2 features (float2). No atomics.
// ---------------------------------------------------------------------------
__global__ __launch_bounds__(256) void agg_kernel(
    const float* __restrict__ h, const int* __restrict__ rowptr,
    const int* __restrict__ cnt, const int* __restrict__ srcIdx,
    const float* __restrict__ dinv, float* __restrict__ out, int nNodes) {
    int wave = threadIdx.x >> 6;
    int lane = threadIdx.x & 63;
    int v = blockIdx.x * 4 + wave;
    if (v >= nNodes) return;
    int start = rowptr[v];
    int n = cnt[v];
    float ax = 0.f, ay = 0.f;
    for (int e = 0; e < n; ++e) {
        int src = srcIdx[start + e];
        float w = dinv[src];
        float2 hv = *(const float2*)&h[(long)src * 128 + lane * 2];
        ax = fmaf(w, hv.x, ax);
        ay = fmaf(w, hv.y, ay);
    }
    float dv = dinv[v];
    *(float2*)&out[(long)v * 128 + lane * 2] = make_float2(ax * dv, ay * dv);
}

// ---------------------------------------------------------------------------
// BN statistics: per-column sum and sum-of-squares via block partials + atomics
// ---------------------------------------------------------------------------
__global__ __launch_bounds__(256) void bnstats(const float* __restrict__ h,
                                               float* __restrict__ sums, int nRows) {
    int col = threadIdx.x & 127;
    int half = threadIdx.x >> 7;
    int chunk = (nRows + gridDim.x - 1) / gridDim.x;
    int r0 = blockIdx.x * chunk;
    int r1 = min(r0 + chunk, nRows);
    float s = 0.f, s2 = 0.f;
    for (int r = r0 + half; r < r1; r += 2) {
        float v = h[(long)r * 128 + col];
        s += v;
        s2 = fmaf(v, v, s2);
    }
    __shared__ float l1[256], l2[256];
    l1[threadIdx.x] = s;
    l2[threadIdx.x] = s2;
    __syncthreads();
    if (half == 0) {
        s = l1[threadIdx.x] + l1[threadIdx.x + 128];
        s2 = l2[threadIdx.x] + l2[threadIdx.x + 128];
        atomicAdd(&sums[col], s);
        atomicAdd(&sums[128 + col], s2);
    }
}

__global__ void bnfin(const float* __restrict__ sums, const float* __restrict__ gamma,
                      const float* __restrict__ beta, float* __restrict__ bn_s,
                      float* __restrict__ bn_t, float invN) {
    int c = threadIdx.x;
    float mean = sums[c] * invN;
    float var = sums[128 + c] * invN - mean * mean;
    float rs = rsqrtf(var + BN_EPS);
    float s = gamma[c] * rs;
    bn_s[c] = s;
    bn_t[c] = beta[c] - mean * s;
}

// ---------------------------------------------------------------------------
// Global mean pool, stage 1: per-slice partial sums, atomicAdd into poolAcc.
// Grid = N_GRAPHS * POOL_SLICES blocks of 256 (2 rows x 128 cols).
// ---------------------------------------------------------------------------
__global__ __launch_bounds__(256) void pool_partial(
    const float* __restrict__ h, const int* __restrict__ batch,
    float* __restrict__ poolAcc, int nNodes) {
    int g = blockIdx.x / POOL_SLICES;
    int s = blockIdx.x % POOL_SLICES;
    // binary search [lo, hi) node range of graph g (batch is sorted)
    int a = 0, b = nNodes;
    while (a < b) { int m = (a + b) >> 1; if (batch[m] < g) a = m + 1; else b = m; }
    int lo = a;
    b = nNodes;
    while (a < b) { int m = (a + b) >> 1; if (batch[m] < g + 1) a = m + 1; else b = m; }
    int hi = a;
    int len = hi - lo;
    int per = (len + POOL_SLICES - 1) / POOL_SLICES;
    int a0 = lo + s * per;
    int a1 = min(a0 + per, hi);
    if (a0 >= a1) return;
    int col = threadIdx.x & 127;
    int half = threadIdx.x >> 7;
    float acc = 0.f;
    for (int v = a0 + half; v < a1; v += 2) acc += h[(long)v * 128 + col];
    __shared__ float l[256];
    l[threadIdx.x] = acc;
    __syncthreads();
    if (half == 0) atomicAdd(&poolAcc[g * 128 + col], l[threadIdx.x] + l[threadIdx.x + 128]);
}

// ---------------------------------------------------------------------------
// MLP head: mean = poolAcc/cnt; relu(xg@Wg1+bg1) @ Wg2 + bg2 -> log_softmax
// ---------------------------------------------------------------------------
__global__ __launch_bounds__(128) void head_kernel(
    const float* __restrict__ poolAcc, const int* __restrict__ batch,
    const float* __restrict__ Wg1, const float* __restrict__ bg1,
    const float* __restrict__ Wg2, const float* __restrict__ bg2,
    float* __restrict__ out, int nNodes) {
    __shared__ float xr[128], tr[128], lg[N_CLASSES], red[2];
    int g = blockIdx.x, t = threadIdx.x;
    // count of nodes in graph g
    int a = 0, b = nNodes;
    while (a < b) { int m = (a + b) >> 1; if (batch[m] < g) a = m + 1; else b = m; }
    int lo = a;
    b = nNodes;
    while (a < b) { int m = (a + b) >> 1; if (batch[m] < g + 1) a = m + 1; else b = m; }
    float cntf = fmaxf((float)(a - lo), 1.0f);
    xr[t] = poolAcc[g * 128 + t] / cntf;
    __syncthreads();
    float s = bg1[t];
    for (int k = 0; k < 128; ++k) s = fmaf(xr[k], Wg1[k * 128 + t], s);
    tr[t] = fmaxf(s, 0.f);
    __syncthreads();
    if (t < N_CLASSES) {
        float s2 = bg2[t];
        for (int k = 0; k < 128; ++k) s2 = fmaf(tr[k], Wg2[k * N_CLASSES + t], s2);
        lg[t] = s2;
    }
    __syncthreads();
    if (t == 0) {
        float m = -1e30f;
        for (int j = 0; j < N_CLASSES; ++j) m = fmaxf(m, lg[j]);
        float se = 0.f;
        for (int j = 0; j < N_CLASSES; ++j) se += expf(lg[j] - m);
        red[0] = m;
        red[1] = logf(se);
    }
    __syncthreads();
    if (t < N_CLASSES) out[g * N_CLASSES + t] = lg[t] - red[0] - red[1];
}

// ---------------------------------------------------------------------------
extern "C" void kernel_launch(void* const* d_in, const int* in_sizes, int n_in,
                              void* d_out, int out_size, void* d_ws, size_t ws_size,
                              hipStream_t stream) {
    const float* x = (const float*)d_in[0];
    const int* edge = (const int*)d_in[1];
    const int* row = edge;
    const int* col = edge + N_EDGES;
    const int* batch = (const int*)d_in[2];
    const float* W0 = (const float*)d_in[3];
    const float* g0 = (const float*)d_in[4];
    const float* b0 = (const float*)d_in[5];
    const float* W1 = (const float*)d_in[6];
    const float* g1 = (const float*)d_in[7];
    const float* b1 = (const float*)d_in[8];
    const float* W2 = (const float*)d_in[9];
    const float* Wg1 = (const float*)d_in[10];
    const float* bg1 = (const float*)d_in[11];
    const float* Wg2 = (const float*)d_in[12];
    const float* bg2 = (const float*)d_in[13];
    float* out = (float*)d_out;

    char* p = (char*)d_ws;
    auto alloc = [&](size_t bytes) {
        void* r = (void*)p;
        p += (bytes + 255) & ~(size_t)255;
        return r;
    };
    float* bufA = (float*)alloc((size_t)N_NODES * 128 * 4);
    float* bufB = (float*)alloc((size_t)N_NODES * 128 * 4);
    float* dinv = (float*)alloc((size_t)N_NODES * 4);
    int* degcnt = (int*)alloc((size_t)N_NODES * 4);
    int* cnt = (int*)alloc((size_t)N_NODES * 4);
    int* rowptr = (int*)alloc((size_t)N_NODES * 4);
    int* wptr = (int*)alloc((size_t)N_NODES * 4);
    int* srcIdx = (int*)alloc((size_t)N_EDGES * 4);
    int* blockSums = (int*)alloc(1024 * 4);
    int* blockOffs = (int*)alloc(1024 * 4);
    float* bnacc = (float*)alloc(256 * 4);
    float* bn_s = (float*)alloc(128 * 4);
    float* bn_t = (float*)alloc(128 * 4);
    float* poolAcc = (float*)alloc(128 * 128 * 4);

    const int E = N_EDGES, N = N_NODES;
    const int scanBlocks = (N + 1023) / 1024;  // 98

    // --- degree + CSR (recomputed every call: deterministic work) ---
    hipMemsetAsync(degcnt, 0, (size_t)N * 4, stream);
    hipMemsetAsync(cnt, 0, (size_t)N * 4, stream);
    count_kernel<<<(E + 255) / 256, 256, 0, stream>>>(row, col, degcnt, cnt, E);
    dinv_kernel<<<(N + 255) / 256, 256, 0, stream>>>(degcnt, dinv, N);
    scanA<<<scanBlocks, 256, 0, stream>>>(cnt, rowptr, blockSums, N);
    scanB<<<1, 128, 0, stream>>>(blockSums, blockOffs, scanBlocks);
    scanC<<<(N + 255) / 256, 256, 0, stream>>>(rowptr, blockOffs, wptr, N);
    fill_kernel<<<(E + 255) / 256, 256, 0, stream>>>(row, col, wptr, srcIdx, E);

    const int gemmGrid = (N + 63) / 64;   // 1563
    const int aggGrid = (N + 3) / 4;      // 25000

    // --- layer 1 ---
    gemm128<<<gemmGrid, 256, 0, stream>>>(x, W0, nullptr, nullptr, bufA, N, 0);
    agg_kernel<<<aggGrid, 256, 0, stream>>>(bufA, rowptr, cnt, srcIdx, dinv, bufB, N);
    hipMemsetAsync(bnacc, 0, 256 * 4, stream);
    bnstats<<<512, 256, 0, stream>>>(bufB, bnacc, N);
    bnfin<<<1, 128, 0, stream>>>(bnacc, g0, b0, bn_s, bn_t, 1.0f / N);

    // --- layer 2 ---
    gemm128<<<gemmGrid, 256, 0, stream>>>(bufB, W1, bn_s, bn_t, bufA, N, 1);
    agg_kernel<<<aggGrid, 256, 0, stream>>>(bufA, rowptr, cnt, srcIdx, dinv, bufB, N);
    hipMemsetAsync(bnacc, 0, 256 * 4, stream);
    bnstats<<<512, 256, 0, stream>>>(bufB, bnacc, N);
    bnfin<<<1, 128, 0, stream>>>(bnacc, g1, b1, bn_s, bn_t, 1.0f / N);

    // --- layer 3 ---
    gemm128<<<gemmGrid, 256, 0, stream>>>(bufB, W2, bn_s, bn_t, bufA, N, 1);
    agg_kernel<<<aggGrid, 256, 0, stream>>>(bufA, rowptr, cnt, srcIdx, dinv, bufB, N);

    // --- pool (parallel partials) + head ---
    hipMemsetAsync(poolAcc, 0, 128 * 128 * 4, stream);
    pool_partial<<<N_GRAPHS * POOL_SLICES, 256, 0, stream>>>(bufB, batch, poolAcc, N);
    head_kernel<<<N_GRAPHS, 128, 0, stream>>>(poolAcc, batch, Wg1, bg1, Wg2, bg2, out, N);
}